// Round 10
// baseline (401.321 us; speedup 1.0000x reference)
//
#include <hip/hip_runtime.h>
#include <hip/hip_bf16.h>

#define N_NODES 100000
#define N_EDGES 600000
#define DIM     128
#define N_REL   8
#define N_GRAPH 64
#define N_LAYER 3
#define NR      (N_NODES * N_REL)   // 800000
#define OVF_CAP 16384                // overflow pairs beyond slot 8 (expected ~0-2 used)

typedef __attribute__((ext_vector_type(4))) float float4v;
typedef __attribute__((ext_vector_type(2))) float float2v;
typedef unsigned long long ull;

// XOR-swizzle, 8-B granules, 128-B rows (B fp8 tiles): 16 granules/row
__device__ __forceinline__ int gswz8(int row, int g) {
    return row * 16 + (g ^ (row & 15));
}

// ---------------- fused prep: DIRECT edge scatter + x0 gather + weight prep + gcnt ----
// CSR sort deleted (r8/r9): histogram's atomicAdd returns the slot index -> scatter
// fused into the edge pass. Slot capacity 8: P(cnt>8 | Poisson 0.75) ~ 4e-7 -> the
// overflow list holds ~0-2 edges TOTAL (r8's capacity-4 global-scan disaster: 366 us).
#define W8_TOTAL (N_LAYER * 9 * 8192)   // 221184
#define PB_HIST  2344                   // ceil(600000/256)
#define PB_GATH  12500                  // 100000*32/256
#define PB_WPRE  864                    // 221184/256
#define PB_BCNT  1                      // binary-search block (NO atomics)
#define PB_TOTAL (PB_HIST + PB_GATH + PB_WPRE + PB_BCNT)

__global__ __launch_bounds__(256) void k_prep(
    const int* __restrict__ ei, const int* __restrict__ et,
    int* __restrict__ cnt, int* __restrict__ srcs8,
    int* __restrict__ ovf, int* __restrict__ ovf_n,
    const int* __restrict__ nt, const float* __restrict__ emb, unsigned int* __restrict__ x8,
    const float* __restrict__ relw, const float* __restrict__ rootw,
    unsigned short* __restrict__ W8,
    const int* __restrict__ batch, int* __restrict__ gcnt)
{
    const int b = blockIdx.x, t = threadIdx.x;
    if (b < PB_HIST) {
        int e = b * 256 + t;
        if (e < N_EDGES) {
            int src = ei[e];
            int seg = ei[N_EDGES + e] * N_REL + et[e];
            int p = atomicAdd(&cnt[seg], 1);
            if (p < 8) {
                srcs8[seg * 8 + p] = src;
            } else {
                int q = atomicAdd(ovf_n, 1);
                if (q < OVF_CAP) { ovf[2 * q] = seg; ovf[2 * q + 1] = src; }
            }
        }
    } else if (b < PB_HIST + PB_GATH) {
        int gid = (b - PB_HIST) * 256 + t;        // < N_NODES*32 exactly
        int n = gid >> 5, up = gid & 31;
        const float* row = emb + (size_t)nt[n] * DIM;
        int p0 = up * 4;
        float f0 = row[((p0 + 0) & 7) * 16 + ((p0 + 0) >> 3)];
        float f1 = row[((p0 + 1) & 7) * 16 + ((p0 + 1) >> 3)];
        float f2 = row[((p0 + 2) & 7) * 16 + ((p0 + 2) >> 3)];
        float f3 = row[((p0 + 3) & 7) * 16 + ((p0 + 3) >> 3)];
        int u = __builtin_amdgcn_cvt_pk_fp8_f32(f0, f1, 0, false);
        u = __builtin_amdgcn_cvt_pk_fp8_f32(f2, f3, u, true);
        x8[gid] = (unsigned int)u;
    } else if (b < PB_HIST + PB_GATH + PB_WPRE) {
        // W8 plane-major (r3 layout): [l][r plane 0..8][n*64 + p2] fp8 pairs
        int gid = (b - PB_HIST - PB_GATH) * 256 + t;   // < W8_TOTAL exactly
        int l = gid / (9 * 8192);
        int rem = gid - l * 9 * 8192;
        int r = rem >> 13;                 // plane 0..8
        int idx = rem & 8191;
        int n = idx >> 6, p2 = idx & 63;
        int pos0 = 2 * p2, pos1 = 2 * p2 + 1;
        int k0 = (pos0 & 7) * 16 + (pos0 >> 3);
        int k1 = (pos1 & 7) * 16 + (pos1 >> 3);
        float w0, w1;
        if (r < 8) {
            const float* base = relw + ((size_t)(l * 8 + r) * 128) * 128 + n;
            w0 = base[(size_t)k0 * 128];
            w1 = base[(size_t)k1 * 128];
        } else {
            const float* base = rootw + (size_t)l * 128 * 128 + n;
            w0 = base[(size_t)k0 * 128];
            w1 = base[(size_t)k1 * 128];
        }
        int pk = __builtin_amdgcn_cvt_pk_fp8_f32(w0, w1, 0, false);
        W8[gid] = (unsigned short)(pk & 0xffff);
    } else {
        // gcnt via binary search over sorted batch (plain stores, no atomics)
        int g = t;
        if (g < N_GRAPH) {
            int lo = 0, hi = N_NODES;
            while (lo < hi) { int mid = (lo + hi) >> 1; if (batch[mid] < g) lo = mid + 1; else hi = mid; }
            int start = lo;
            lo = 0; hi = N_NODES;
            while (lo < hi) { int mid = (lo + hi) >> 1; if (batch[mid] < g + 1) lo = mid + 1; else hi = mid; }
            gcnt[g] = lo - start;
        }
    }
}

// ---------------- FUSED agg + MFMA GEMM (r9 base) + POOL FUSED INTO LAST LAYER --------
// r9 verified at 370 us total (gemm 75.5). ROUND-10 CHANGE (single variable): the
// last-layer dispatch skips the fp8 pack/store and mean-pools its POST-RELU fp32
// acc directly into gsum (natural col order) — k_pool (12.8 MB re-read) deleted.
// batch is sorted: a thread's two 4-row runs span ~1-2 graphs -> ~8 atomicAdds
// per thread to gsum[g*128+col] (1.6M atomics over 8k addresses, low contention).
#define BM2 128
__global__ __launch_bounds__(256, 2) void k_gemm(
    const unsigned int* __restrict__ x8in,  // [N][32] fp8 rows (pi order)
    unsigned int* __restrict__ x8out,       // [N][32] fp8 rows (unused when last)
    const unsigned short* __restrict__ W8,  // [9][128n][64kp] fp8 pairs (this layer)
    const float* __restrict__ bias,         // [128]
    const int* __restrict__ cnt,            // [NR], seg = dst*8 + rel
    const int* __restrict__ srcs8,          // [NR*8] slot storage
    const int* __restrict__ ovf,            // [OVF_CAP*2] (seg,src) pairs beyond slot 8
    const int* __restrict__ ovf_n,
    const int* __restrict__ batch,          // [N] sorted graph ids (last layer only)
    float* __restrict__ gsum,               // [64][128] natural-col pool sums
    int isLast)
{
    __shared__ __align__(16) ull Bls[4096];  // 2 x 16 KB ping-pong (B)
    __shared__ __align__(16) ull Als[2048];  // 4 waves x 4 KB private A chunk
    const int t = threadIdx.x;
    const int wv = t >> 6, lane = t & 63;
    const int quad = lane >> 4, l15 = lane & 15;
    const int oct = lane >> 3, h = lane & 7;
    const int m0 = blockIdx.x * BM2;
    const int gn = m0 + wv * 32 + (lane >> 1);       // node owned by this lane-pair
    const int nodeC = (gn < N_NODES) ? gn : 0;       // clamped (invalid rows discarded)
    const int f = lane & 1;

    float4v acc[2][8];
#pragma unroll
    for (int nt = 0; nt < 8; ++nt) {
        float bc = bias[nt * 16 + l15];
        acc[0][nt] = (float4v){bc, bc, bc, bc};
        acc[1][nt] = (float4v){bc, bc, bc, bc};
    }

    const ull* Xr = (const ull*)x8in;
    const uint4* x4p = (const uint4*)x8in;
    ull* AlsW = Als + wv * 512;              // this wave's region (512 ull)
    uint4* Als4 = (uint4*)AlsW;

    ull bR[8], aR[8];
    uint4 u0[4], u1[4];
    int cc[4], s2v[4], s3v[4];

#define ACCUM(U) do {                                                  \
        A0 += __builtin_amdgcn_cvt_pk_f32_fp8((int)(U).x, false);      \
        A1 += __builtin_amdgcn_cvt_pk_f32_fp8((int)(U).x, true);       \
        A2 += __builtin_amdgcn_cvt_pk_f32_fp8((int)(U).y, false);      \
        A3 += __builtin_amdgcn_cvt_pk_f32_fp8((int)(U).y, true);       \
        A4 += __builtin_amdgcn_cvt_pk_f32_fp8((int)(U).z, false);      \
        A5 += __builtin_amdgcn_cvt_pk_f32_fp8((int)(U).z, true);       \
        A6 += __builtin_amdgcn_cvt_pk_f32_fp8((int)(U).w, false);      \
        A7 += __builtin_amdgcn_cvt_pk_f32_fp8((int)(U).w, true);       \
    } while (0)

    // meta loads for chunk rr: cnt + slot values f, 2+f — ALL static addresses
    auto ld_meta = [&](int rr, int& cl, int& s0, int& s2) {
        int seg = nodeC * 8 + rr;
        cl = cnt[seg];
        s0 = srcs8[seg * 8 + f];
        s2 = srcs8[seg * 8 + 2 + f];
    };
    // shuffle per-octet metadata, issue first-2 gathers (held across iteration)
    auto gat_issue = [&](int cl, int sl0, int sl2) {
#pragma unroll
        for (int nn = 0; nn < 4; ++nn) {
            int lw = nn * 8 + oct;
            cc[nn] = __shfl(cl, lw * 2);
            int s0 = __shfl(sl0, lw * 2);
            int s1 = __shfl(sl0, lw * 2 + 1);
            s2v[nn] = __shfl(sl2, lw * 2);
            s3v[nn] = __shfl(sl2, lw * 2 + 1);
            if (cc[nn] > 0) u0[nn] = x4p[(size_t)s0 * 8 + h];
            if (cc[nn] > 1) u1[nn] = x4p[(size_t)s1 * 8 + h];
        }
    };
    // issue k=2,3 gathers, accumulate (slot order), rare 4..7 slots, pack, write Als
    auto agg_consume = [&](int rr) {
        uint4 u2[4], u3[4];
#pragma unroll
        for (int nn = 0; nn < 4; ++nn) {
            if (cc[nn] > 2) u2[nn] = x4p[(size_t)s2v[nn] * 8 + h];
            if (cc[nn] > 3) u3[nn] = x4p[(size_t)s3v[nn] * 8 + h];
        }
#pragma unroll
        for (int nn = 0; nn < 4; ++nn) {
            int lw = nn * 8 + oct;
            float2v A0 = {0.f, 0.f}, A1 = {0.f, 0.f}, A2 = {0.f, 0.f}, A3 = {0.f, 0.f};
            float2v A4 = {0.f, 0.f}, A5 = {0.f, 0.f}, A6 = {0.f, 0.f}, A7 = {0.f, 0.f};
            if (cc[nn] > 0) ACCUM(u0[nn]);
            if (cc[nn] > 1) ACCUM(u1[nn]);
            if (cc[nn] > 2) ACCUM(u2[nn]);
            if (cc[nn] > 3) ACCUM(u3[nn]);
            if (cc[nn] > 4) {                 // slots 4..7: direct static loads (~1100 segs total)
                int seg = (m0 + wv * 32 + lw) * 8 + rr;
                int mc = cc[nn] < 8 ? cc[nn] : 8;
#pragma unroll 1
                for (int k = 4; k < mc; ++k) {
                    uint4 uu = x4p[(size_t)srcs8[seg * 8 + k] * 8 + h];
                    ACCUM(uu);
                }
                if (cc[nn] > 8) {             // beyond 8: overflow list (~0-2 entries total)
                    int ovn = ovf_n[0];
                    if (ovn > OVF_CAP) ovn = OVF_CAP;
#pragma unroll 1
                    for (int j = 0; j < ovn; ++j) {
                        if (ovf[2 * j] == seg) {
                            uint4 uu = x4p[(size_t)ovf[2 * j + 1] * 8 + h];
                            ACCUM(uu);
                        }
                    }
                }
            }
            float inv = (cc[nn] > 0) ? 1.0f / (float)cc[nn] : 0.f;
            float2v iv = {inv, inv};
            A0 *= iv; A1 *= iv; A2 *= iv; A3 *= iv;
            A4 *= iv; A5 *= iv; A6 *= iv; A7 *= iv;
            int w0 = __builtin_amdgcn_cvt_pk_fp8_f32(A0.x, A0.y, 0, false);
            w0 = __builtin_amdgcn_cvt_pk_fp8_f32(A1.x, A1.y, w0, true);
            int w1 = __builtin_amdgcn_cvt_pk_fp8_f32(A2.x, A2.y, 0, false);
            w1 = __builtin_amdgcn_cvt_pk_fp8_f32(A3.x, A3.y, w1, true);
            int w2 = __builtin_amdgcn_cvt_pk_fp8_f32(A4.x, A4.y, 0, false);
            w2 = __builtin_amdgcn_cvt_pk_fp8_f32(A5.x, A5.y, w2, true);
            int w3 = __builtin_amdgcn_cvt_pk_fp8_f32(A6.x, A6.y, 0, false);
            w3 = __builtin_amdgcn_cvt_pk_fp8_f32(A7.x, A7.y, w3, true);
            uint4 w; w.x = (unsigned int)w0; w.y = (unsigned int)w1;
            w.z = (unsigned int)w2; w.w = (unsigned int)w3;
            Als4[(lw >> 4) * 128 + h * 16 + ((lw & 15) ^ h)] = w;
        }
    };

    // ---- prologue: B(0) + gathers(0) in flight + meta(1) loaded ----
    {
        const ull* Wc = (const ull*)W8;
#pragma unroll
        for (int i = 0; i < 8; ++i) bR[i] = Wc[t + 256 * i];
    }
    int clA, sl0A, sl2A, clN, sl0N, sl2N;
    ld_meta(0, clA, sl0A, sl2A);
    gat_issue(clA, sl0A, sl2A);      // gathers chunk 0 (consumed at iter 0 top)
    ld_meta(1, clA, sl0A, sl2A);     // meta chunk 1 (registers free after gat_issue)
#pragma unroll
    for (int i = 0; i < 8; ++i) {
        int idx = t + 256 * i;
        Bls[gswz8(idx >> 4, idx & 15)] = bR[i];
    }
    __syncthreads();

    // iter c: consume(c) [gathers from iter c-1 -> FULL-iteration cover] |
    //         meta(c+2) | gathers(c+1) | B(c+1) | MFMA(c) | B store | barrier
#pragma unroll
    for (int c = 0; c < 9; ++c) {
        const int cur = (c & 1) * 2048;
        if (c <= 7) agg_consume(c);                  // writes Als(c); MFMA(c) reads it
        if (c <= 5) ld_meta(c + 2, clN, sl0N, sl2N);
        if (c <= 6) gat_issue(clA, sl0A, sl2A);      // gathers chunk c+1
        if (c < 8) {                                 // B prefetch chunk c+1
            const ull* Wc = (const ull*)(W8 + (size_t)(c + 1) * 8192);
#pragma unroll
            for (int i = 0; i < 8; ++i) bR[i] = Wc[t + 256 * i];
        }
        if (c == 7) {                                // root A from x8 rows
#pragma unroll
            for (int i = 0; i < 8; ++i) {
                int rt = i >> 2, kk = i & 3;
                aR[i] = Xr[(size_t)(m0 + wv * 32 + rt * 16 + l15) * 16 + kk * 4 + quad];
            }
        }
#pragma unroll
        for (int kk = 0; kk < 4; ++kk) {
            long long a0, a1;
            if (c == 8) {
                a0 = (long long)aR[kk];
                a1 = (long long)aR[4 + kk];
            } else {
                int j4 = kk * 4 + quad;        // byte-pair group 0..15
                int h2 = j4 >> 1, hf = j4 & 1;
                int slot = ((h2 * 16 + (l15 ^ h2)) << 1) | hf;
                a0 = (long long)AlsW[slot];
                a1 = (long long)AlsW[256 + slot];
            }
            int g = kk * 4 + quad;
#pragma unroll
            for (int nt = 0; nt < 8; ++nt) {
                long long b8 = (long long)Bls[cur + (nt * 16 + l15) * 16 + (g ^ l15)];
                acc[0][nt] = __builtin_amdgcn_mfma_f32_16x16x32_fp8_fp8(a0, b8, acc[0][nt], 0, 0, 0);
                acc[1][nt] = __builtin_amdgcn_mfma_f32_16x16x32_fp8_fp8(a1, b8, acc[1][nt], 0, 0, 0);
            }
        }
        if (c < 8) {
            const int nxt = ((c + 1) & 1) * 2048;
#pragma unroll
            for (int i = 0; i < 8; ++i) {
                int idx = t + 256 * i;
                Bls[nxt + gswz8(idx >> 4, idx & 15)] = bR[i];
            }
            __syncthreads();
        }
        clA = clN; sl0A = sl0N; sl2A = sl2N;
    }
#undef ACCUM

    if (!isLast) {
        // ---- epilogue: relu, fp8 pack (pi order rows) ----
        ull* outs = (ull*)x8out;
#pragma unroll
        for (int rt = 0; rt < 2; ++rt) {
#pragma unroll
            for (int i = 0; i < 4; ++i) {
                int row = m0 + wv * 32 + rt * 16 + quad * 4 + i;
                float v0 = acc[rt][0][i], v1 = acc[rt][1][i];
                float v2 = acc[rt][2][i], v3 = acc[rt][3][i];
                float v4 = acc[rt][4][i], v5 = acc[rt][5][i];
                float v6 = acc[rt][6][i], v7 = acc[rt][7][i];
                v0 = v0 > 0.f ? v0 : 0.f;  v1 = v1 > 0.f ? v1 : 0.f;
                v2 = v2 > 0.f ? v2 : 0.f;  v3 = v3 > 0.f ? v3 : 0.f;
                v4 = v4 > 0.f ? v4 : 0.f;  v5 = v5 > 0.f ? v5 : 0.f;
                v6 = v6 > 0.f ? v6 : 0.f;  v7 = v7 > 0.f ? v7 : 0.f;
                int lo = __builtin_amdgcn_cvt_pk_fp8_f32(v0, v1, 0, false);
                lo = __builtin_amdgcn_cvt_pk_fp8_f32(v2, v3, lo, true);
                int hi = __builtin_amdgcn_cvt_pk_fp8_f32(v4, v5, 0, false);
                hi = __builtin_amdgcn_cvt_pk_fp8_f32(v6, v7, hi, true);
                if (row < N_NODES) {
                    ull w = ((ull)(unsigned int)hi << 32) | (unsigned int)lo;
                    outs[(size_t)row * 16 + l15] = w;
                }
            }
        }
    } else {
        // ---- fused mean-pool epilogue: post-relu fp32, natural-col gsum ----
        // batch sorted -> graph id changes rarely within a thread's 8 rows.
        float s[8];
#pragma unroll
        for (int nt = 0; nt < 8; ++nt) s[nt] = 0.f;
        int curg = -1;
#pragma unroll
        for (int rt = 0; rt < 2; ++rt) {
#pragma unroll
            for (int i = 0; i < 4; ++i) {
                int row = m0 + wv * 32 + rt * 16 + quad * 4 + i;
                if (row < N_NODES) {
                    int gb = batch[row];
                    if (gb != curg) {
                        if (curg >= 0) {
#pragma unroll
                            for (int nt = 0; nt < 8; ++nt)
                                atomicAdd(&gsum[curg * 128 + nt * 16 + l15], s[nt]);
#pragma unroll
                            for (int nt = 0; nt < 8; ++nt) s[nt] = 0.f;
                        }
                        curg = gb;
                    }
#pragma unroll
                    for (int nt = 0; nt < 8; ++nt) {
                        float v = acc[rt][nt][i];
                        s[nt] += v > 0.f ? v : 0.f;
                    }
                }
            }
        }
        if (curg >= 0) {
#pragma unroll
            for (int nt = 0; nt < 8; ++nt)
                atomicAdd(&gsum[curg * 128 + nt * 16 + l15], s[nt]);
        }
    }
}

// ---------------- MLP heads (fp32; gsum is natural-col order from fused pool) --------
__global__ __launch_bounds__(128) void k_heads(
    const float* __restrict__ gsum, const int* __restrict__ gcnt,
    const float* __restrict__ rw1, const float* __restrict__ rb1,
    const float* __restrict__ rw2, const float* __restrict__ rb2,
    const float* __restrict__ sw1, const float* __restrict__ sb1,
    const float* __restrict__ sw2, const float* __restrict__ sb2,
    float* __restrict__ out) {
    __shared__ float g[128];
    __shared__ float parts[2];
    int b = blockIdx.x, t = threadIdx.x;
    int c = gcnt[b];
    float invc = 1.0f / (float)(c > 0 ? c : 1);
    g[t] = gsum[b * 128 + t] * invc;               // natural order: no permute
    __syncthreads();
    float acc = rb1[t];
    for (int d = 0; d < 128; ++d) acc += g[d] * rw1[d * 128 + t];
    float h = acc > 0.f ? acc : 0.f;
    float p = h * rw2[t];
    for (int o = 32; o > 0; o >>= 1) p += __shfl_down(p, o);
    if ((t & 63) == 0) parts[t >> 6] = p;
    __syncthreads();
    if (t == 0) out[b] = parts[0] + parts[1] + rb2[0];
    __syncthreads();
    acc = sb1[t];
    for (int d = 0; d < 128; ++d) acc += g[d] * sw1[d * 128 + t];
    h = acc > 0.f ? acc : 0.f;
    p = h * sw2[t];
    for (int o = 32; o > 0; o >>= 1) p += __shfl_down(p, o);
    if ((t & 63) == 0) parts[t >> 6] = p;
    __syncthreads();
    if (t == 0) out[64 + b] = parts[0] + parts[1] + sb2[0];
}

extern "C" void kernel_launch(void* const* d_in, const int* in_sizes, int n_in,
                              void* d_out, int out_size, void* d_ws, size_t ws_size,
                              hipStream_t stream) {
    const int*   node_type  = (const int*)d_in[0];
    const int*   edge_index = (const int*)d_in[1];
    const int*   edge_type  = (const int*)d_in[2];
    const int*   batch      = (const int*)d_in[3];
    const float* node_emb   = (const float*)d_in[4];
    const float* rel_w      = (const float*)d_in[5];
    const float* root_w     = (const float*)d_in[6];
    const float* bias       = (const float*)d_in[7];
    const float* rw1        = (const float*)d_in[8];
    const float* rb1        = (const float*)d_in[9];
    const float* rw2        = (const float*)d_in[10];
    const float* rb2        = (const float*)d_in[11];
    const float* sw1        = (const float*)d_in[12];
    const float* sb1        = (const float*)d_in[13];
    const float* sw2        = (const float*)d_in[14];
    const float* sb2        = (const float*)d_in[15];
    float* out = (float*)d_out;

    char* ws = (char*)d_ws;
    size_t off = 0;
    auto alloc = [&](size_t bytes) -> void* {
        void* p = ws + off;
        off += (bytes + 255) & ~(size_t)255;
        return p;
    };
    // ---- workspace (~56 MB total) ----
    unsigned int*   x8a    = (unsigned int*)alloc((size_t)N_NODES * 32 * 4);  // 12.8 MB
    unsigned int*   x8b    = (unsigned int*)alloc((size_t)N_NODES * 32 * 4);  // 12.8 MB
    int*            cnt    = (int*)alloc((size_t)NR * 4);                     // 3.2 MB
    int*            srcs8  = (int*)alloc((size_t)NR * 8 * 4);                 // 25.6 MB
    int*            ovf    = (int*)alloc((size_t)OVF_CAP * 2 * 4);            // 0.13 MB
    unsigned short* W8     = (unsigned short*)alloc((size_t)W8_TOTAL * 2);    // 0.44 MB
    float*          gsum   = (float*)alloc((64 * 128 + 64 + 64) * 4);
    int*            gcnt   = (int*)(gsum + 64 * 128);
    int*            ovf_n  = (int*)(gsum + 64 * 128 + 64);
    if (off > ws_size) return;                     // fail visibly if ws too small

    // memset cnt + (gsum|gcnt|ovf_n), then fused prep (direct scatter — no sort)
    hipMemsetAsync(cnt, 0, (size_t)NR * 4, stream);
    hipMemsetAsync(gsum, 0, (size_t)(64 * 128 + 64 + 64) * 4, stream);
    k_prep<<<PB_TOTAL, 256, 0, stream>>>(edge_index, edge_type, cnt, srcs8, ovf, ovf_n,
                                         node_type, node_emb, x8a,
                                         rel_w, root_w, W8, batch, gcnt);

    unsigned int* xcur = x8a;
    unsigned int* xnext = x8b;
    const int gb = (N_NODES + BM2 - 1) / BM2;      // 782
    for (int l = 0; l < N_LAYER; ++l) {
        const unsigned short* W8l = W8 + (size_t)l * 9 * 8192;
        const float* bl = bias + (size_t)l * 128;
        k_gemm<<<gb, 256, 0, stream>>>(xcur, xnext, W8l, bl, cnt, srcs8, ovf, ovf_n,
                                       batch, gsum, (l == N_LAYER - 1) ? 1 : 0);
        unsigned int* tmp = xcur; xcur = xnext; xnext = tmp;
    }

    // heads (pool already fused into last gemm; gsum is natural-col order)
    k_heads<<<64, 128, 0, stream>>>(gsum, gcnt, rw1, rb1, rw2, rb2,
                                    sw1, sb1, sw2, sb2, out);
}

// Round 11
// 365.341 us; speedup vs baseline: 1.0985x; 1.0985x over previous
//
#include <hip/hip_runtime.h>
#include <hip/hip_bf16.h>

#define N_NODES 100000
#define N_EDGES 600000
#define DIM     128
#define N_REL   8
#define N_GRAPH 64
#define N_LAYER 3
#define NR      (N_NODES * N_REL)   // 800000
#define OVF_CAP 16384                // overflow pairs beyond slot 8 (expected ~0-2 used)

typedef __attribute__((ext_vector_type(4))) float float4v;
typedef __attribute__((ext_vector_type(2))) float float2v;
typedef unsigned long long ull;

// XOR-swizzle, 8-B granules, 128-B rows (B fp8 tiles): 16 granules/row
__device__ __forceinline__ int gswz8(int row, int g) {
    return row * 16 + (g ^ (row & 15));
}

#define W8_TOTAL (N_LAYER * 9 * 8192)   // 221184
#define PB_HIST  2344                   // ceil(600000/256)
#define PB_GATH  12500                  // 100000*32/256
#define PB_WPRE  864                    // 221184/256
#define PB_BCNT  1                      // binary-search block (NO atomics)

// ---------------- k_prep split (r11, observational): edges vs rest ----------------
// Phases touch disjoint data (cnt/srcs8 | x8 | W8 | gcnt) -> split is behavior-
// neutral and makes each phase visible in the rocprof top-5 (stack = 133 us,
// never yet attributed). Slot capacity 8: P(cnt>8 | Poisson 0.75) ~ 4e-7.
__global__ __launch_bounds__(256) void k_prep_edges(
    const int* __restrict__ ei, const int* __restrict__ et,
    int* __restrict__ cnt, int* __restrict__ srcs8,
    int* __restrict__ ovf, int* __restrict__ ovf_n)
{
    int e = blockIdx.x * 256 + threadIdx.x;
    if (e < N_EDGES) {
        int src = ei[e];
        int seg = ei[N_EDGES + e] * N_REL + et[e];
        int p = atomicAdd(&cnt[seg], 1);
        if (p < 8) {
            srcs8[seg * 8 + p] = src;
        } else {
            int q = atomicAdd(ovf_n, 1);
            if (q < OVF_CAP) { ovf[2 * q] = seg; ovf[2 * q + 1] = src; }
        }
    }
}

__global__ __launch_bounds__(256) void k_prep_rest(
    const int* __restrict__ nt, const float* __restrict__ emb, unsigned int* __restrict__ x8,
    const float* __restrict__ relw, const float* __restrict__ rootw,
    unsigned short* __restrict__ W8,
    const int* __restrict__ batch, int* __restrict__ gcnt)
{
    const int b = blockIdx.x, t = threadIdx.x;
    if (b < PB_GATH) {
        int gid = b * 256 + t;                    // < N_NODES*32 exactly
        int n = gid >> 5, up = gid & 31;
        const float* row = emb + (size_t)nt[n] * DIM;
        int p0 = up * 4;
        float f0 = row[((p0 + 0) & 7) * 16 + ((p0 + 0) >> 3)];
        float f1 = row[((p0 + 1) & 7) * 16 + ((p0 + 1) >> 3)];
        float f2 = row[((p0 + 2) & 7) * 16 + ((p0 + 2) >> 3)];
        float f3 = row[((p0 + 3) & 7) * 16 + ((p0 + 3) >> 3)];
        int u = __builtin_amdgcn_cvt_pk_fp8_f32(f0, f1, 0, false);
        u = __builtin_amdgcn_cvt_pk_fp8_f32(f2, f3, u, true);
        x8[gid] = (unsigned int)u;
    } else if (b < PB_GATH + PB_WPRE) {
        // W8 plane-major (r3 layout): [l][r plane 0..8][n*64 + p2] fp8 pairs
        int gid = (b - PB_GATH) * 256 + t;        // < W8_TOTAL exactly
        int l = gid / (9 * 8192);
        int rem = gid - l * 9 * 8192;
        int r = rem >> 13;                 // plane 0..8
        int idx = rem & 8191;
        int n = idx >> 6, p2 = idx & 63;
        int pos0 = 2 * p2, pos1 = 2 * p2 + 1;
        int k0 = (pos0 & 7) * 16 + (pos0 >> 3);
        int k1 = (pos1 & 7) * 16 + (pos1 >> 3);
        float w0, w1;
        if (r < 8) {
            const float* base = relw + ((size_t)(l * 8 + r) * 128) * 128 + n;
            w0 = base[(size_t)k0 * 128];
            w1 = base[(size_t)k1 * 128];
        } else {
            const float* base = rootw + (size_t)l * 128 * 128 + n;
            w0 = base[(size_t)k0 * 128];
            w1 = base[(size_t)k1 * 128];
        }
        int pk = __builtin_amdgcn_cvt_pk_fp8_f32(w0, w1, 0, false);
        W8[gid] = (unsigned short)(pk & 0xffff);
    } else {
        // gcnt via binary search over sorted batch (plain stores, no atomics)
        int g = t;
        if (g < N_GRAPH) {
            int lo = 0, hi = N_NODES;
            while (lo < hi) { int mid = (lo + hi) >> 1; if (batch[mid] < g) lo = mid + 1; else hi = mid; }
            int start = lo;
            lo = 0; hi = N_NODES;
            while (lo < hi) { int mid = (lo + hi) >> 1; if (batch[mid] < g + 1) lo = mid + 1; else hi = mid; }
            gcnt[g] = lo - start;
        }
    }
}

// ---------------- FUSED agg + MFMA GEMM (r9 base) + pool w/ LDS pre-reduction --------
// r10 post-mortem: fused pool's 1.6M device atomicAdds onto 8K floats (256 hot
// lines x 8 non-coherent XCD L2s -> line ping-pong) took the last-layer dispatch
// 75.5 -> 116.5 us. r11 fix (Guideline 12): reduce into LDS first (reusing Bls;
// a 128-row block spans <=2 graphs since N/B=1562), then <=512 one-per-(graph,col)
// global atomics per block -> ~200K total, ~13 blocks/graph contention.
#define BM2 128
__global__ __launch_bounds__(256, 2) void k_gemm(
    const unsigned int* __restrict__ x8in,  // [N][32] fp8 rows (pi order)
    unsigned int* __restrict__ x8out,       // [N][32] fp8 rows (unused when last)
    const unsigned short* __restrict__ W8,  // [9][128n][64kp] fp8 pairs (this layer)
    const float* __restrict__ bias,         // [128]
    const int* __restrict__ cnt,            // [NR], seg = dst*8 + rel
    const int* __restrict__ srcs8,          // [NR*8] slot storage
    const int* __restrict__ ovf,            // [OVF_CAP*2] (seg,src) pairs beyond slot 8
    const int* __restrict__ ovf_n,
    const int* __restrict__ batch,          // [N] sorted graph ids (last layer only)
    float* __restrict__ gsum,               // [64][128] natural-col pool sums
    int isLast)
{
    __shared__ __align__(16) ull Bls[4096];  // 2 x 16 KB ping-pong (B); reused by pool
    __shared__ __align__(16) ull Als[2048];  // 4 waves x 4 KB private A chunk
    const int t = threadIdx.x;
    const int wv = t >> 6, lane = t & 63;
    const int quad = lane >> 4, l15 = lane & 15;
    const int oct = lane >> 3, h = lane & 7;
    const int m0 = blockIdx.x * BM2;
    const int gn = m0 + wv * 32 + (lane >> 1);       // node owned by this lane-pair
    const int nodeC = (gn < N_NODES) ? gn : 0;       // clamped (invalid rows discarded)
    const int f = lane & 1;

    float4v acc[2][8];
#pragma unroll
    for (int nt = 0; nt < 8; ++nt) {
        float bc = bias[nt * 16 + l15];
        acc[0][nt] = (float4v){bc, bc, bc, bc};
        acc[1][nt] = (float4v){bc, bc, bc, bc};
    }

    const ull* Xr = (const ull*)x8in;
    const uint4* x4p = (const uint4*)x8in;
    ull* AlsW = Als + wv * 512;              // this wave's region (512 ull)
    uint4* Als4 = (uint4*)AlsW;

    ull bR[8], aR[8];
    uint4 u0[4], u1[4];
    int cc[4], s2v[4], s3v[4];

#define ACCUM(U) do {                                                  \
        A0 += __builtin_amdgcn_cvt_pk_f32_fp8((int)(U).x, false);      \
        A1 += __builtin_amdgcn_cvt_pk_f32_fp8((int)(U).x, true);       \
        A2 += __builtin_amdgcn_cvt_pk_f32_fp8((int)(U).y, false);      \
        A3 += __builtin_amdgcn_cvt_pk_f32_fp8((int)(U).y, true);       \
        A4 += __builtin_amdgcn_cvt_pk_f32_fp8((int)(U).z, false);      \
        A5 += __builtin_amdgcn_cvt_pk_f32_fp8((int)(U).z, true);       \
        A6 += __builtin_amdgcn_cvt_pk_f32_fp8((int)(U).w, false);      \
        A7 += __builtin_amdgcn_cvt_pk_f32_fp8((int)(U).w, true);       \
    } while (0)

    // meta loads for chunk rr: cnt + slot values f, 2+f — ALL static addresses
    auto ld_meta = [&](int rr, int& cl, int& s0, int& s2) {
        int seg = nodeC * 8 + rr;
        cl = cnt[seg];
        s0 = srcs8[seg * 8 + f];
        s2 = srcs8[seg * 8 + 2 + f];
    };
    // shuffle per-octet metadata, issue first-2 gathers (held across iteration)
    auto gat_issue = [&](int cl, int sl0, int sl2) {
#pragma unroll
        for (int nn = 0; nn < 4; ++nn) {
            int lw = nn * 8 + oct;
            cc[nn] = __shfl(cl, lw * 2);
            int s0 = __shfl(sl0, lw * 2);
            int s1 = __shfl(sl0, lw * 2 + 1);
            s2v[nn] = __shfl(sl2, lw * 2);
            s3v[nn] = __shfl(sl2, lw * 2 + 1);
            if (cc[nn] > 0) u0[nn] = x4p[(size_t)s0 * 8 + h];
            if (cc[nn] > 1) u1[nn] = x4p[(size_t)s1 * 8 + h];
        }
    };
    // issue k=2,3 gathers, accumulate (slot order), rare 4..7 slots, pack, write Als
    auto agg_consume = [&](int rr) {
        uint4 u2[4], u3[4];
#pragma unroll
        for (int nn = 0; nn < 4; ++nn) {
            if (cc[nn] > 2) u2[nn] = x4p[(size_t)s2v[nn] * 8 + h];
            if (cc[nn] > 3) u3[nn] = x4p[(size_t)s3v[nn] * 8 + h];
        }
#pragma unroll
        for (int nn = 0; nn < 4; ++nn) {
            int lw = nn * 8 + oct;
            float2v A0 = {0.f, 0.f}, A1 = {0.f, 0.f}, A2 = {0.f, 0.f}, A3 = {0.f, 0.f};
            float2v A4 = {0.f, 0.f}, A5 = {0.f, 0.f}, A6 = {0.f, 0.f}, A7 = {0.f, 0.f};
            if (cc[nn] > 0) ACCUM(u0[nn]);
            if (cc[nn] > 1) ACCUM(u1[nn]);
            if (cc[nn] > 2) ACCUM(u2[nn]);
            if (cc[nn] > 3) ACCUM(u3[nn]);
            if (cc[nn] > 4) {                 // slots 4..7: direct static loads (~1100 segs total)
                int seg = (m0 + wv * 32 + lw) * 8 + rr;
                int mc = cc[nn] < 8 ? cc[nn] : 8;
#pragma unroll 1
                for (int k = 4; k < mc; ++k) {
                    uint4 uu = x4p[(size_t)srcs8[seg * 8 + k] * 8 + h];
                    ACCUM(uu);
                }
                if (cc[nn] > 8) {             // beyond 8: overflow list (~0-2 entries total)
                    int ovn = ovf_n[0];
                    if (ovn > OVF_CAP) ovn = OVF_CAP;
#pragma unroll 1
                    for (int j = 0; j < ovn; ++j) {
                        if (ovf[2 * j] == seg) {
                            uint4 uu = x4p[(size_t)ovf[2 * j + 1] * 8 + h];
                            ACCUM(uu);
                        }
                    }
                }
            }
            float inv = (cc[nn] > 0) ? 1.0f / (float)cc[nn] : 0.f;
            float2v iv = {inv, inv};
            A0 *= iv; A1 *= iv; A2 *= iv; A3 *= iv;
            A4 *= iv; A5 *= iv; A6 *= iv; A7 *= iv;
            int w0 = __builtin_amdgcn_cvt_pk_fp8_f32(A0.x, A0.y, 0, false);
            w0 = __builtin_amdgcn_cvt_pk_fp8_f32(A1.x, A1.y, w0, true);
            int w1 = __builtin_amdgcn_cvt_pk_fp8_f32(A2.x, A2.y, 0, false);
            w1 = __builtin_amdgcn_cvt_pk_fp8_f32(A3.x, A3.y, w1, true);
            int w2 = __builtin_amdgcn_cvt_pk_fp8_f32(A4.x, A4.y, 0, false);
            w2 = __builtin_amdgcn_cvt_pk_fp8_f32(A5.x, A5.y, w2, true);
            int w3 = __builtin_amdgcn_cvt_pk_fp8_f32(A6.x, A6.y, 0, false);
            w3 = __builtin_amdgcn_cvt_pk_fp8_f32(A7.x, A7.y, w3, true);
            uint4 w; w.x = (unsigned int)w0; w.y = (unsigned int)w1;
            w.z = (unsigned int)w2; w.w = (unsigned int)w3;
            Als4[(lw >> 4) * 128 + h * 16 + ((lw & 15) ^ h)] = w;
        }
    };

    // ---- prologue: B(0) + gathers(0) in flight + meta(1) loaded ----
    {
        const ull* Wc = (const ull*)W8;
#pragma unroll
        for (int i = 0; i < 8; ++i) bR[i] = Wc[t + 256 * i];
    }
    int clA, sl0A, sl2A, clN, sl0N, sl2N;
    ld_meta(0, clA, sl0A, sl2A);
    gat_issue(clA, sl0A, sl2A);      // gathers chunk 0 (consumed at iter 0 top)
    ld_meta(1, clA, sl0A, sl2A);     // meta chunk 1 (registers free after gat_issue)
#pragma unroll
    for (int i = 0; i < 8; ++i) {
        int idx = t + 256 * i;
        Bls[gswz8(idx >> 4, idx & 15)] = bR[i];
    }
    __syncthreads();

    // iter c: consume(c) [gathers from iter c-1 -> FULL-iteration cover] |
    //         meta(c+2) | gathers(c+1) | B(c+1) | MFMA(c) | B store | barrier
#pragma unroll
    for (int c = 0; c < 9; ++c) {
        const int cur = (c & 1) * 2048;
        if (c <= 7) agg_consume(c);                  // writes Als(c); MFMA(c) reads it
        if (c <= 5) ld_meta(c + 2, clN, sl0N, sl2N);
        if (c <= 6) gat_issue(clA, sl0A, sl2A);      // gathers chunk c+1
        if (c < 8) {                                 // B prefetch chunk c+1
            const ull* Wc = (const ull*)(W8 + (size_t)(c + 1) * 8192);
#pragma unroll
            for (int i = 0; i < 8; ++i) bR[i] = Wc[t + 256 * i];
        }
        if (c == 7) {                                // root A from x8 rows
#pragma unroll
            for (int i = 0; i < 8; ++i) {
                int rt = i >> 2, kk = i & 3;
                aR[i] = Xr[(size_t)(m0 + wv * 32 + rt * 16 + l15) * 16 + kk * 4 + quad];
            }
        }
#pragma unroll
        for (int kk = 0; kk < 4; ++kk) {
            long long a0, a1;
            if (c == 8) {
                a0 = (long long)aR[kk];
                a1 = (long long)aR[4 + kk];
            } else {
                int j4 = kk * 4 + quad;        // byte-pair group 0..15
                int h2 = j4 >> 1, hf = j4 & 1;
                int slot = ((h2 * 16 + (l15 ^ h2)) << 1) | hf;
                a0 = (long long)AlsW[slot];
                a1 = (long long)AlsW[256 + slot];
            }
            int g = kk * 4 + quad;
#pragma unroll
            for (int nt = 0; nt < 8; ++nt) {
                long long b8 = (long long)Bls[cur + (nt * 16 + l15) * 16 + (g ^ l15)];
                acc[0][nt] = __builtin_amdgcn_mfma_f32_16x16x32_fp8_fp8(a0, b8, acc[0][nt], 0, 0, 0);
                acc[1][nt] = __builtin_amdgcn_mfma_f32_16x16x32_fp8_fp8(a1, b8, acc[1][nt], 0, 0, 0);
            }
        }
        if (c < 8) {
            const int nxt = ((c + 1) & 1) * 2048;
#pragma unroll
            for (int i = 0; i < 8; ++i) {
                int idx = t + 256 * i;
                Bls[nxt + gswz8(idx >> 4, idx & 15)] = bR[i];
            }
            __syncthreads();
        }
        clA = clN; sl0A = sl0N; sl2A = sl2N;
    }
#undef ACCUM

    if (!isLast) {
        // ---- epilogue: relu, fp8 pack (pi order rows) ----
        ull* outs = (ull*)x8out;
#pragma unroll
        for (int rt = 0; rt < 2; ++rt) {
#pragma unroll
            for (int i = 0; i < 4; ++i) {
                int row = m0 + wv * 32 + rt * 16 + quad * 4 + i;
                float v0 = acc[rt][0][i], v1 = acc[rt][1][i];
                float v2 = acc[rt][2][i], v3 = acc[rt][3][i];
                float v4 = acc[rt][4][i], v5 = acc[rt][5][i];
                float v6 = acc[rt][6][i], v7 = acc[rt][7][i];
                v0 = v0 > 0.f ? v0 : 0.f;  v1 = v1 > 0.f ? v1 : 0.f;
                v2 = v2 > 0.f ? v2 : 0.f;  v3 = v3 > 0.f ? v3 : 0.f;
                v4 = v4 > 0.f ? v4 : 0.f;  v5 = v5 > 0.f ? v5 : 0.f;
                v6 = v6 > 0.f ? v6 : 0.f;  v7 = v7 > 0.f ? v7 : 0.f;
                int lo = __builtin_amdgcn_cvt_pk_fp8_f32(v0, v1, 0, false);
                lo = __builtin_amdgcn_cvt_pk_fp8_f32(v2, v3, lo, true);
                int hi = __builtin_amdgcn_cvt_pk_fp8_f32(v4, v5, 0, false);
                hi = __builtin_amdgcn_cvt_pk_fp8_f32(v6, v7, hi, true);
                if (row < N_NODES) {
                    ull w = ((ull)(unsigned int)hi << 32) | (unsigned int)lo;
                    outs[(size_t)row * 16 + l15] = w;
                }
            }
        }
    } else {
        // ---- fused mean-pool epilogue, r11: per-block LDS pre-reduction ----
        __syncthreads();                       // all waves done reading Bls
        float* gred = (float*)Bls;             // reuse 2 KB of B LDS: [4][128]
        for (int k2 = t; k2 < 512; k2 += 256) gred[k2] = 0.f;
        __syncthreads();
        int r1 = m0 + BM2 - 1; if (r1 >= N_NODES) r1 = N_NODES - 1;
        const int gLo = batch[m0];             // m0 < N_NODES always (grid sizing)
        const bool fits = (batch[r1] - gLo) < 4;   // block-uniform
        float s[8];
#pragma unroll
        for (int nt = 0; nt < 8; ++nt) s[nt] = 0.f;
        int curg = -1;
#pragma unroll
        for (int rt = 0; rt < 2; ++rt) {
#pragma unroll
            for (int i = 0; i < 4; ++i) {
                int row = m0 + wv * 32 + rt * 16 + quad * 4 + i;
                if (row < N_NODES) {
                    int gb = batch[row];
                    if (gb != curg) {
                        if (curg >= 0) {
                            if (fits) {
#pragma unroll
                                for (int nt = 0; nt < 8; ++nt)
                                    if (s[nt] != 0.f) atomicAdd(&gred[(curg - gLo) * 128 + nt * 16 + l15], s[nt]);
                            } else {
#pragma unroll
                                for (int nt = 0; nt < 8; ++nt)
                                    atomicAdd(&gsum[curg * 128 + nt * 16 + l15], s[nt]);
                            }
#pragma unroll
                            for (int nt = 0; nt < 8; ++nt) s[nt] = 0.f;
                        }
                        curg = gb;
                    }
#pragma unroll
                    for (int nt = 0; nt < 8; ++nt) {
                        float v = acc[rt][nt][i];
                        s[nt] += v > 0.f ? v : 0.f;
                    }
                }
            }
        }
        if (curg >= 0) {
            if (fits) {
#pragma unroll
                for (int nt = 0; nt < 8; ++nt)
                    if (s[nt] != 0.f) atomicAdd(&gred[(curg - gLo) * 128 + nt * 16 + l15], s[nt]);
            } else {
#pragma unroll
                for (int nt = 0; nt < 8; ++nt)
                    atomicAdd(&gsum[curg * 128 + nt * 16 + l15], s[nt]);
            }
        }
        __syncthreads();
        if (fits) {
            for (int k2 = t; k2 < 512; k2 += 256) {
                float v = gred[k2];
                if (v != 0.f)
                    atomicAdd(&gsum[(gLo + (k2 >> 7)) * 128 + (k2 & 127)], v);
            }
        }
    }
}

// ---------------- MLP heads (fp32; gsum is natural-col order from fused pool) --------
__global__ __launch_bounds__(128) void k_heads(
    const float* __restrict__ gsum, const int* __restrict__ gcnt,
    const float* __restrict__ rw1, const float* __restrict__ rb1,
    const float* __restrict__ rw2, const float* __restrict__ rb2,
    const float* __restrict__ sw1, const float* __restrict__ sb1,
    const float* __restrict__ sw2, const float* __restrict__ sb2,
    float* __restrict__ out) {
    __shared__ float g[128];
    __shared__ float parts[2];
    int b = blockIdx.x, t = threadIdx.x;
    int c = gcnt[b];
    float invc = 1.0f / (float)(c > 0 ? c : 1);
    g[t] = gsum[b * 128 + t] * invc;               // natural order: no permute
    __syncthreads();
    float acc = rb1[t];
    for (int d = 0; d < 128; ++d) acc += g[d] * rw1[d * 128 + t];
    float h = acc > 0.f ? acc : 0.f;
    float p = h * rw2[t];
    for (int o = 32; o > 0; o >>= 1) p += __shfl_down(p, o);
    if ((t & 63) == 0) parts[t >> 6] = p;
    __syncthreads();
    if (t == 0) out[b] = parts[0] + parts[1] + rb2[0];
    __syncthreads();
    acc = sb1[t];
    for (int d = 0; d < 128; ++d) acc += g[d] * sw1[d * 128 + t];
    h = acc > 0.f ? acc : 0.f;
    p = h * sw2[t];
    for (int o = 32; o > 0; o >>= 1) p += __shfl_down(p, o);
    if ((t & 63) == 0) parts[t >> 6] = p;
    __syncthreads();
    if (t == 0) out[64 + b] = parts[0] + parts[1] + sb2[0];
}

extern "C" void kernel_launch(void* const* d_in, const int* in_sizes, int n_in,
                              void* d_out, int out_size, void* d_ws, size_t ws_size,
                              hipStream_t stream) {
    const int*   node_type  = (const int*)d_in[0];
    const int*   edge_index = (const int*)d_in[1];
    const int*   edge_type  = (const int*)d_in[2];
    const int*   batch      = (const int*)d_in[3];
    const float* node_emb   = (const float*)d_in[4];
    const float* rel_w      = (const float*)d_in[5];
    const float* root_w     = (const float*)d_in[6];
    const float* bias       = (const float*)d_in[7];
    const float* rw1        = (const float*)d_in[8];
    const float* rb1        = (const float*)d_in[9];
    const float* rw2        = (const float*)d_in[10];
    const float* rb2        = (const float*)d_in[11];
    const float* sw1        = (const float*)d_in[12];
    const float* sb1        = (const float*)d_in[13];
    const float* sw2        = (const float*)d_in[14];
    const float* sb2        = (const float*)d_in[15];
    float* out = (float*)d_out;

    char* ws = (char*)d_ws;
    size_t off = 0;
    auto alloc = [&](size_t bytes) -> void* {
        void* p = ws + off;
        off += (bytes + 255) & ~(size_t)255;
        return p;
    };
    // ---- workspace (~56 MB total) ----
    unsigned int*   x8a    = (unsigned int*)alloc((size_t)N_NODES * 32 * 4);  // 12.8 MB
    unsigned int*   x8b    = (unsigned int*)alloc((size_t)N_NODES * 32 * 4);  // 12.8 MB
    int*            cnt    = (int*)alloc((size_t)NR * 4);                     // 3.2 MB
    int*            srcs8  = (int*)alloc((size_t)NR * 8 * 4);                 // 25.6 MB
    int*            ovf    = (int*)alloc((size_t)OVF_CAP * 2 * 4);            // 0.13 MB
    unsigned short* W8     = (unsigned short*)alloc((size_t)W8_TOTAL * 2);    // 0.44 MB
    float*          gsum   = (float*)alloc((64 * 128 + 64 + 64) * 4);
    int*            gcnt   = (int*)(gsum + 64 * 128);
    int*            ovf_n  = (int*)(gsum + 64 * 128 + 64);
    if (off > ws_size) return;                     // fail visibly if ws too small

    // memset cnt + (gsum|gcnt|ovf_n), then prep (edges scatter || gather/wpre/gcnt)
    hipMemsetAsync(cnt, 0, (size_t)NR * 4, stream);
    hipMemsetAsync(gsum, 0, (size_t)(64 * 128 + 64 + 64) * 4, stream);
    k_prep_edges<<<PB_HIST, 256, 0, stream>>>(edge_index, edge_type, cnt, srcs8, ovf, ovf_n);
    k_prep_rest<<<PB_GATH + PB_WPRE + PB_BCNT, 256, 0, stream>>>(node_type, node_emb, x8a,
                                                                 rel_w, root_w, W8, batch, gcnt);

    unsigned int* xcur = x8a;
    unsigned int* xnext = x8b;
    const int gb = (N_NODES + BM2 - 1) / BM2;      // 782
    for (int l = 0; l < N_LAYER; ++l) {
        const unsigned short* W8l = W8 + (size_t)l * 9 * 8192;
        const float* bl = bias + (size_t)l * 128;
        k_gemm<<<gb, 256, 0, stream>>>(xcur, xnext, W8l, bl, cnt, srcs8, ovf, ovf_n,
                                       batch, gsum, (l == N_LAYER - 1) ? 1 : 0);
        unsigned int* tmp = xcur; xcur = xnext; xnext = tmp;
    }

    // heads (pool already fused into last gemm; gsum is natural-col order)
    k_heads<<<64, 128, 0, stream>>>(gsum, gcnt, rw1, rb1, rw2, rb2,
                                    sw1, sb1, sw2, sb2, out);
}